// Round 6
// baseline (825.285 us; speedup 1.0000x reference)
//
#include <hip/hip_runtime.h>
#include <cstdint>

#define NTOK 8192
#define CDIM 1024
#define HDIM 1408
#define HSDIM 2816
#define NEXP 8

typedef __attribute__((ext_vector_type(8))) short s8v;
typedef __attribute__((ext_vector_type(4))) float f4v;
typedef __attribute__((ext_vector_type(8))) unsigned short u16x8;

__device__ __forceinline__ unsigned short f2bf(float f) {
    unsigned int u = __float_as_uint(f);
    unsigned int r = (u + 0x7fffu + ((u >> 16) & 1u)) >> 16;  // RNE
    return (unsigned short)r;
}
__device__ __forceinline__ float bf2f(unsigned short u) {
    return __uint_as_float(((unsigned int)u) << 16);
}

__device__ __forceinline__ void gld_lds16(const unsigned short* g, unsigned short* l) {
    __builtin_amdgcn_global_load_lds(
        (const __attribute__((address_space(1))) void*)g,
        (__attribute__((address_space(3))) void*)l, 16, 0, 0);
}

// ---------------- fused prep kernel ----------------
// Block ranges (longest-job-first): weight transposes, then x->bf16 cvt,
// then router. 128x128 transpose tiles, bf16-in-LDS, transpose-on-write:
// reads 512B/row granule, writes 256B/row granule (vs 256/128 of the old
// 64x64 version, which measured 0.85 TB/s).

#define PT_A (11 * 8 * 16)          // W1,W2 [1024][1408] (1408)
#define PT_B (8 * 11 * 8)           // W3 [1408][1024] (704)
#define PT_C (22 * 8 * 2)           // Ws1,Ws2 [1024][2816] (352)
#define PT_D (8 * 22)               // Ws3 [2816][1024] (176)
#define P_CVT 8192                  // NTOK*CDIM/4 float4 / 256
#define P_RTR 2048                  // 8192 tokens, 4 waves/block
#define P_TOTAL (PT_A + PT_B + PT_C + PT_D + P_CVT + P_RTR)

// LDS layout: Tt[c][r], c=0..127 output rows, stride 132 halfwords.
// Load: thread (r=t>>1, ch=t&1) reads 256B of input row r, scalar-writes
// transposed. Store: thread (c=t>>1, hh=t&1) reads r-contiguous b64 pairs,
// stores 16B chunks; 2 threads/output-row -> 256B contiguous.
__device__ __forceinline__ void transpose_tile128(
    unsigned short* Tt, const float* __restrict__ in, unsigned short* __restrict__ out,
    int R, int Cc, int bx, int by) {
    const int t = threadIdx.x;
    const int r0 = by * 128, c0 = bx * 128;
    {
        const int r = t >> 1, ch = t & 1;
        const float* src = in + (size_t)(r0 + r) * Cc + c0 + ch * 64;
        unsigned short* tr = Tt + (ch * 64) * 132 + r;
#pragma unroll
        for (int i = 0; i < 16; i++) {
            float4 v = *(const float4*)(src + 4 * i);
            tr[(4 * i + 0) * 132] = f2bf(v.x);
            tr[(4 * i + 1) * 132] = f2bf(v.y);
            tr[(4 * i + 2) * 132] = f2bf(v.z);
            tr[(4 * i + 3) * 132] = f2bf(v.w);
        }
    }
    __syncthreads();
    {
        const int c = t >> 1, hh = t & 1;
        unsigned short* dst = out + (size_t)(c0 + c) * R + r0 + hh * 64;
        const unsigned short* sr = Tt + c * 132 + hh * 64;
#pragma unroll
        for (int i = 0; i < 8; i++) {
            ushort4 a = *(const ushort4*)(sr + 8 * i);
            ushort4 b = *(const ushort4*)(sr + 8 * i + 4);
            u16x8 w;
            w[0] = a.x; w[1] = a.y; w[2] = a.z; w[3] = a.w;
            w[4] = b.x; w[5] = b.y; w[6] = b.z; w[7] = b.w;
            *(u16x8*)(dst + 8 * i) = w;
        }
    }
}

__global__ __launch_bounds__(256) void prep_kernel(
    const float* __restrict__ x, const float* __restrict__ Wg,
    const float* __restrict__ W1, const float* __restrict__ W2, const float* __restrict__ W3,
    const float* __restrict__ Ws1, const float* __restrict__ Ws2, const float* __restrict__ Ws3,
    unsigned short* __restrict__ xb,
    unsigned short* __restrict__ w1t, unsigned short* __restrict__ w2t,
    unsigned short* __restrict__ w3t,
    unsigned short* __restrict__ ws1t, unsigned short* __restrict__ ws2t,
    unsigned short* __restrict__ ws3t,
    int* __restrict__ idxK, float* __restrict__ probK, int* __restrict__ meta) {
    __shared__ unsigned short Tt[128 * 132];  // 33.8 KB
    int bid = blockIdx.x;
    const int tid = threadIdx.x;

    if (bid < PT_A) {
        // ---- W1/W2 [e][1024][1408] -> [e][1408][1024] ----
        const int bx = bid % 11, by = (bid / 11) % 8, z = bid / 88;
        const float* in = (z < 8) ? W1 : W2;
        unsigned short* out = (z < 8) ? w1t : w2t;
        const int zz = (z < 8) ? z : z - 8;
        const size_t bs = (size_t)CDIM * HDIM;
        transpose_tile128(Tt, in + zz * bs, out + zz * bs, CDIM, HDIM, bx, by);
        return;
    }
    bid -= PT_A;
    if (bid < PT_B) {
        // ---- W3 [e][1408][1024] -> [e][1024][1408] ----
        const int bx = bid % 8, by = (bid / 8) % 11, z = bid / 88;
        const size_t bs = (size_t)HDIM * CDIM;
        transpose_tile128(Tt, W3 + z * bs, w3t + z * bs, HDIM, CDIM, bx, by);
        return;
    }
    bid -= PT_B;
    if (bid < PT_C) {
        // ---- Ws1/Ws2 [1024][2816] -> [2816][1024] ----
        const int bx = bid % 22, by = (bid / 22) % 8, z = bid / 176;
        const float* in = (z == 0) ? Ws1 : Ws2;
        unsigned short* out = (z == 0) ? ws1t : ws2t;
        transpose_tile128(Tt, in, out, CDIM, HSDIM, bx, by);
        return;
    }
    bid -= PT_C;
    if (bid < PT_D) {
        // ---- Ws3 [2816][1024] -> [1024][2816] ----
        const int bx = bid % 8, by = bid / 8;
        transpose_tile128(Tt, Ws3, ws3t, HSDIM, CDIM, bx, by);
        return;
    }
    bid -= PT_D;
    if (bid < P_CVT) {
        // ---- x -> bf16 ----
        const int i = bid * 256 + tid;
        float4 v = ((const float4*)x)[i];
        ushort4 o;
        o.x = f2bf(v.x); o.y = f2bf(v.y); o.z = f2bf(v.z); o.w = f2bf(v.w);
        ((ushort4*)xb)[i] = o;
        return;
    }
    bid -= P_CVT;
    {
        // ---- router: one wave per token (fp32 inputs to keep top-k exact) ----
        const int t = bid * 4 + (tid >> 6);
        const int lane = tid & 63;
        const float* xr = x + (size_t)t * CDIM;
        float acc[NEXP];
#pragma unroll
        for (int e = 0; e < NEXP; e++) acc[e] = 0.f;
        for (int c = lane; c < CDIM; c += 64) {
            float xv = xr[c];
            const float* wr = Wg + c * NEXP;
#pragma unroll
            for (int e = 0; e < NEXP; e++) acc[e] += xv * wr[e];
        }
#pragma unroll
        for (int e = 0; e < NEXP; e++)
            for (int off = 32; off > 0; off >>= 1)
                acc[e] += __shfl_down(acc[e], off, 64);
        if (lane == 0) {
            int b0 = 0; float v0 = acc[0];
#pragma unroll
            for (int e = 1; e < NEXP; e++) if (acc[e] > v0) { v0 = acc[e]; b0 = e; }
            int b1 = -1; float v1 = -1e30f;
#pragma unroll
            for (int e = 0; e < NEXP; e++) if (e != b0 && acc[e] > v1) { v1 = acc[e]; b1 = e; }
            float p0 = 1.f / (1.f + __expf(v1 - v0));
            idxK[2 * t] = b0; idxK[2 * t + 1] = b1;
            probK[2 * t] = p0; probK[2 * t + 1] = 1.f - p0;
            atomicAdd(&meta[b0], 1);
            atomicAdd(&meta[b1], 1);
        }
    }
}

// meta: [0..7] counts, [8..15] offsets, [16..23] cursor
__global__ void offsets_kernel(int* meta) {
    int s = 0;
    for (int e = 0; e < NEXP; e++) { meta[8 + e] = s; meta[16 + e] = s; s += meta[e]; }
}

__global__ void fill_kernel(const int* __restrict__ idxK, const float* __restrict__ probK,
                            int* __restrict__ meta, int* __restrict__ rowT, float* __restrict__ rowW,
                            int* __restrict__ tokSlot) {
    int t = blockIdx.x * 256 + threadIdx.x;
    if (t >= NTOK) return;
#pragma unroll
    for (int k = 0; k < 2; k++) {
        int e = idxK[2 * t + k];
        int p = atomicAdd(&meta[16 + e], 1);
        rowT[p] = t;
        rowW[p] = probK[2 * t + k];
        tokSlot[2 * t + k] = p;
    }
}

// ---------------- fused gate GEMM: H = silu(A@W1) * (A@W2), m201 8-phase ----
// BM=256, virtual BN'=256 (B1/B2 interleaved at 16-col granularity -> 128 real
// H-cols, silu pairs intra-wave), BK=64, 8 waves (2Mx4N), 128 KB LDS dbuf.
// Region-death staging: s0-A dead after P3 (staged P4,P5), s0-B after P4
// (P6,P7), s1-A after P7 (P8,P1'), s1-B after P8 (P2',P3'). Counted
// vmcnt(2)+barrier at P4 and P8 only. Bank swizzle carried on global source.
__global__ __launch_bounds__(512, 2) void gemm12_kernel(
    const unsigned short* __restrict__ xb,
    const unsigned short* __restrict__ w1, const unsigned short* __restrict__ w2,
    const unsigned short* __restrict__ ws1, const unsigned short* __restrict__ ws2,
    unsigned short* __restrict__ hE, unsigned short* __restrict__ hS,
    const int* __restrict__ rowT, const int* __restrict__ meta) {
    const int id = blockIdx.x;
    int z, m0, n0; bool SH;
    if (id < 880) { SH = false; z = id & 7; int q = id >> 3; m0 = (q % 10) * 256; n0 = (q / 10) * 128; }
    else          { SH = true;  z = 8; int q = id - 880; m0 = (q & 31) * 256; n0 = (q >> 5) * 128; }
    const int M = SH ? NTOK : meta[z];
    const int base = SH ? 0 : meta[8 + z];
    if (m0 >= M) return;

    const unsigned short* B1 = SH ? ws1 : w1 + (size_t)z * HDIM * CDIM;
    const unsigned short* B2 = SH ? ws2 : w2 + (size_t)z * HDIM * CDIM;

    __shared__ unsigned short L[65536];  // 128 KB

    const int tid = threadIdx.x;
    const int srow = tid >> 3;                        // 0..63
    const int cg = ((tid & 7) ^ (srow & 7)) << 3;     // pre-swizzled global chunk

    // staging pointers: A rows and interleaved-B' rows, per (half h, unit u)
    const unsigned short* pA[2][2];
    const unsigned short* pB[2][2];
#pragma unroll
    for (int h = 0; h < 2; h++)
#pragma unroll
        for (int u = 0; u < 2; u++) {
            int lr = h * 128 + u * 64 + srow;
            int am = m0 + lr; am = am < M ? am : M - 1;
            int gr = SH ? am : rowT[base + am];
            pA[h][u] = xb + (size_t)gr * CDIM + cg;
            int n = lr;  // virtual B' row
            int hcol = n0 + ((n >> 5) << 4) + (n & 15);
            pB[h][u] = (((n >> 4) & 1) ? B2 : B1) + (size_t)hcol * CDIM + cg;
        }

    const int w = tid >> 6, lane = tid & 63;
    const int wr = w >> 2, wc = w & 3;
    const int quad = lane >> 4, l15 = lane & 15;
    int ck[2];
    ck[0] = (quad ^ (l15 & 7)) << 3;
    ck[1] = ((4 + quad) ^ (l15 & 7)) << 3;
    const int ArdBase = wr * 8192 + l15 * 64;
    const int BrdBase = 16384 + (wc >> 1) * 8192 + ((wc & 1) * 64 + l15) * 64;

    f4v acc[8][4];
#pragma unroll
    for (int i = 0; i < 8; i++)
#pragma unroll
        for (int j = 0; j < 4; j++) {
            f4v zz = {0.f, 0.f, 0.f, 0.f};
            acc[i][j] = zz;
        }

    s8v aF[4][2], bF[2][2];

    auto SA = [&](int s, int h, int kt) {
        gld_lds16(pA[h][0] + (size_t)kt * 64, L + s * 32768 + h * 8192 + tid * 8);
        gld_lds16(pA[h][1] + (size_t)kt * 64, L + s * 32768 + h * 8192 + 4096 + tid * 8);
    };
    auto SB = [&](int s, int h, int kt) {
        gld_lds16(pB[h][0] + (size_t)kt * 64, L + s * 32768 + 16384 + h * 8192 + tid * 8);
        gld_lds16(pB[h][1] + (size_t)kt * 64, L + s * 32768 + 16384 + h * 8192 + 4096 + tid * 8);
    };
    auto RA = [&](int s, int mb) {
#pragma unroll
        for (int j = 0; j < 4; j++)
#pragma unroll
            for (int k = 0; k < 2; k++)
                aF[j][k] = *(const s8v*)(L + s * 32768 + ArdBase + (mb + j) * 1024 + ck[k]);
    };
    auto RB = [&](int s, int nb) {
#pragma unroll
        for (int j = 0; j < 2; j++)
#pragma unroll
            for (int k = 0; k < 2; k++)
                bF[j][k] = *(const s8v*)(L + s * 32768 + BrdBase + (nb + j) * 1024 + ck[k]);
    };
    auto MF = [&](int mb, int nb) {
#pragma unroll
        for (int k = 0; k < 2; k++)
#pragma unroll
            for (int j = 0; j < 4; j++)
#pragma unroll
                for (int n = 0; n < 2; n++)
                    acc[mb + j][nb + n] = __builtin_amdgcn_mfma_f32_16x16x32_bf16(
                        aF[j][k], bF[n][k], acc[mb + j][nb + n], 0, 0, 0);
    };

#define BAR() __builtin_amdgcn_s_barrier()
#define LGKM0() do { asm volatile("s_waitcnt lgkmcnt(0)" ::: "memory"); \
                     __builtin_amdgcn_sched_barrier(0); } while (0)
#define VM2() do { asm volatile("s_waitcnt vmcnt(2)" ::: "memory"); \
                   __builtin_amdgcn_sched_barrier(0); } while (0)
#define PRIO1() __builtin_amdgcn_s_setprio(1)
#define PRIO0() __builtin_amdgcn_s_setprio(0)

    // prologue: tile0 -> slot0 (4 half-tiles), tile1 A0 -> slot1
    SA(0, 0, 0); SA(0, 1, 0); SB(0, 0, 0); SB(0, 1, 0); SA(1, 0, 1);
    VM2(); BAR();

#pragma unroll 1
    for (int i = 0; i < 8; i++) {
        const int k1 = 2 * i + 1;
        const int k2 = (2 * i + 2 < 16) ? 2 * i + 2 : 15;
        const int k3 = (2 * i + 3 < 16) ? 2 * i + 3 : 15;
        // P1: s0 quadrant (m0-3, n0-1)
        RA(0, 0); RB(0, 0); SA(1, 1, k1);
        BAR(); LGKM0(); PRIO1(); MF(0, 0); PRIO0(); BAR();
        // P2: (m0-3, n2-3)
        RB(0, 2); SB(1, 0, k1);
        BAR(); LGKM0(); PRIO1(); MF(0, 2); PRIO0(); BAR();
        // P3: (m4-7, n0-1)
        RA(0, 4); RB(0, 0); SB(1, 1, k1);
        BAR(); LGKM0(); PRIO1(); MF(4, 0); PRIO0(); BAR();
        // P4: (m4-7, n2-3) + counted wait for slot1's tile
        RB(0, 2); SA(0, 0, k2);
        BAR(); LGKM0(); PRIO1(); MF(4, 2); PRIO0(); VM2(); BAR();
        // P5: s1 quadrant (m0-3, n0-1)
        RA(1, 0); RB(1, 0); SA(0, 1, k2);
        BAR(); LGKM0(); PRIO1(); MF(0, 0); PRIO0(); BAR();
        // P6: (m0-3, n2-3)
        RB(1, 2); SB(0, 0, k2);
        BAR(); LGKM0(); PRIO1(); MF(0, 2); PRIO0(); BAR();
        // P7: (m4-7, n0-1)
        RA(1, 4); RB(1, 0); SB(0, 1, k2);
        BAR(); LGKM0(); PRIO1(); MF(4, 0); PRIO0(); BAR();
        // P8: (m4-7, n2-3) + counted wait for slot0's next tile
        RB(1, 2); SA(1, 0, k3);
        BAR(); LGKM0(); PRIO1(); MF(4, 2); PRIO0(); VM2(); BAR();
    }
    asm volatile("s_waitcnt vmcnt(0)" ::: "memory");

#undef BAR
#undef LGKM0
#undef VM2
#undef PRIO1
#undef PRIO0

    // epilogue: silu(B1-col) * B2-col pairs; wave covers 128 rows x 32 H-cols
#pragma unroll
    for (int mf = 0; mf < 8; mf++) {
#pragma unroll
        for (int r = 0; r < 4; r++) {
            int gm = m0 + wr * 128 + mf * 16 + quad * 4 + r;
            if (gm < M) {
                unsigned short* hrow = SH ? hS + (size_t)gm * HSDIM
                                          : hE + (size_t)(base + gm) * HDIM;
                const int cbase = n0 + wc * 32;
#pragma unroll
                for (int p = 0; p < 2; p++) {
                    float z1 = acc[mf][2 * p][r];
                    float z2 = acc[mf][2 * p + 1][r];
                    float hv = (z1 / (1.f + __expf(-z1))) * z2;
                    hrow[cbase + p * 16 + l15] = f2bf(hv);
                }
            }
        }
    }
}

// ---------------- merged down-proj GEMM (R1-verified form) ----------------
// Longest-job-first: shared blocks (K=2816, 2x work) dispatch at ids [0,512).
__global__ __launch_bounds__(256) void gemm3_kernel(
    const unsigned short* __restrict__ hE, const unsigned short* __restrict__ hS,
    const unsigned short* __restrict__ w3, const unsigned short* __restrict__ ws3,
    float* __restrict__ Out, unsigned short* __restrict__ pE,
    const int* __restrict__ rowT, const float* __restrict__ rowW, const int* __restrict__ meta) {
    const int id = blockIdx.x;
    int z, m0, n0; bool SH;
    if (id < 512) { SH = true;  z = 8; int q = id; m0 = (q & 63) * 128; n0 = (q >> 6) * 128; }
    else          { SH = false; int r = id - 512; z = r & 7; int q = r >> 3; m0 = (q % 20) * 128; n0 = (q / 20) * 128; }
    const int M = SH ? NTOK : meta[z];
    const int base = SH ? 0 : meta[8 + z];
    if (m0 >= M) return;
    const int K = SH ? HSDIM : HDIM;
    const unsigned short* A = SH ? hS : hE;
    const unsigned short* B = SH ? ws3 : w3 + (size_t)z * CDIM * HDIM;

    __shared__ unsigned short L[16384];

    const int tid = threadIdx.x;
    const int srow = tid >> 2;
    const int key = (tid >> 3) & 3;
    const int co = ((tid & 3) ^ key) << 3;

    int am0 = m0 + srow;       am0 = am0 < M ? am0 : M - 1;
    int am1 = m0 + 64 + srow;  am1 = am1 < M ? am1 : M - 1;
    const unsigned short* a0p = A + (size_t)(base + am0) * K + co;
    const unsigned short* a1p = A + (size_t)(base + am1) * K + co;
    const unsigned short* b0p = B + (size_t)(n0 + srow) * K + co;
    const unsigned short* b1p = B + (size_t)(n0 + 64 + srow) * K + co;

    const int w = tid >> 6, lane = tid & 63;
    const int wm = (w >> 1) * 64, wn = (w & 1) * 64;
    const int quad = lane >> 4, l15 = lane & 15;
    const int rcx = (quad ^ ((l15 >> 1) & 3)) << 3;

    f4v acc[4][4];
#pragma unroll
    for (int i = 0; i < 4; i++)
#pragma unroll
        for (int j = 0; j < 4; j++) {
            f4v zz = {0.f, 0.f, 0.f, 0.f};
            acc[i][j] = zz;
        }

#define STAGE3(b, k0) do { \
        gld_lds16(a0p + (k0), L + (b) * 4096 + tid * 8); \
        gld_lds16(a1p + (k0), L + (b) * 4096 + 2048 + tid * 8); \
        gld_lds16(b0p + (k0), L + 8192 + (b) * 4096 + tid * 8); \
        gld_lds16(b1p + (k0), L + 8192 + (b) * 4096 + 2048 + tid * 8); } while (0)

    auto compute = [&](int b) {
        const unsigned short* Ab = L + b * 4096;
        const unsigned short* Bb = L + 8192 + b * 4096;
        s8v af[4], bf[4];
#pragma unroll
        for (int mt = 0; mt < 4; mt++)
            af[mt] = *(const s8v*)(Ab + (wm + mt * 16 + l15) * 32 + rcx);
#pragma unroll
        for (int nt = 0; nt < 4; nt++)
            bf[nt] = *(const s8v*)(Bb + (wn + nt * 16 + l15) * 32 + rcx);
#pragma unroll
        for (int mt = 0; mt < 4; mt++)
#pragma unroll
            for (int nt = 0; nt < 4; nt++)
                acc[mt][nt] = __builtin_amdgcn_mfma_f32_16x16x32_bf16(af[mt], bf[nt], acc[mt][nt], 0, 0, 0);
    };

    const int NS = K / 32;
    STAGE3(0, 0);
    __syncthreads();
#pragma unroll 1
    for (int ks = 0; ks < NS; ks++) {
        if (ks + 1 < NS) STAGE3((ks + 1) & 1, (ks + 1) * 32);
        compute(ks & 1);
        __syncthreads();
    }
#undef STAGE3

#pragma unroll
    for (int mt = 0; mt < 4; mt++) {
#pragma unroll
        for (int r = 0; r < 4; r++) {
            int gm = m0 + wm + mt * 16 + quad * 4 + r;
            if (gm < M) {
                if (SH) {
                    size_t o = (size_t)gm * CDIM + n0 + wn + l15;
#pragma unroll
                    for (int nt = 0; nt < 4; nt++)
                        Out[o + nt * 16] = acc[mt][nt][r];
                } else {
                    size_t o = (size_t)(base + gm) * CDIM + n0 + wn + l15;
#pragma unroll
                    for (int nt = 0; nt < 4; nt++)
                        pE[o + nt * 16] = f2bf(acc[mt][nt][r]);
                }
            }
        }
    }
}

// ---------------- combine: out[t] += w0*pE[s0] + w1*pE[s1] ----------------
__global__ __launch_bounds__(256) void combine_kernel(
    float* __restrict__ Out, const unsigned short* __restrict__ pE,
    const int* __restrict__ tokSlot, const float* __restrict__ rowW) {
    const int t = blockIdx.x;
    const int c = threadIdx.x * 4;
    const int s0 = tokSlot[2 * t], s1 = tokSlot[2 * t + 1];
    const float w0 = rowW[s0], w1 = rowW[s1];
    float* op = Out + (size_t)t * CDIM + c;
    float4 o = *(float4*)op;
    ushort4 a = *(const ushort4*)(pE + (size_t)s0 * CDIM + c);
    ushort4 b = *(const ushort4*)(pE + (size_t)s1 * CDIM + c);
    o.x += w0 * bf2f(a.x) + w1 * bf2f(b.x);
    o.y += w0 * bf2f(a.y) + w1 * bf2f(b.y);
    o.z += w0 * bf2f(a.z) + w1 * bf2f(b.z);
    o.w += w0 * bf2f(a.w) + w1 * bf2f(b.w);
    *(float4*)op = o;
}

// ---------------- launch ----------------

extern "C" void kernel_launch(void* const* d_in, const int* in_sizes, int n_in,
                              void* d_out, int out_size, void* d_ws, size_t ws_size,
                              hipStream_t stream) {
    const float* x   = (const float*)d_in[0];
    const float* Wg  = (const float*)d_in[1];
    const float* W1  = (const float*)d_in[2];
    const float* W2  = (const float*)d_in[3];
    const float* W3  = (const float*)d_in[4];
    const float* Ws1 = (const float*)d_in[5];
    const float* Ws2 = (const float*)d_in[6];
    const float* Ws3 = (const float*)d_in[7];
    float* out = (float*)d_out;

    char* p = (char*)d_ws;
    auto carve = [&](size_t bytes) {
        char* r = p;
        p += (bytes + 255) & ~(size_t)255;
        return r;
    };
    unsigned short* xb   = (unsigned short*)carve((size_t)NTOK * CDIM * 2);
    unsigned short* w1t  = (unsigned short*)carve((size_t)NEXP * HDIM * CDIM * 2);
    unsigned short* w2t  = (unsigned short*)carve((size_t)NEXP * HDIM * CDIM * 2);
    unsigned short* w3t  = (unsigned short*)carve((size_t)NEXP * CDIM * HDIM * 2);
    unsigned short* ws1t = (unsigned short*)carve((size_t)HSDIM * CDIM * 2);
    unsigned short* ws2t = (unsigned short*)carve((size_t)HSDIM * CDIM * 2);
    unsigned short* ws3t = (unsigned short*)carve((size_t)CDIM * HSDIM * 2);
    unsigned short* hE   = (unsigned short*)carve((size_t)2 * NTOK * HDIM * 2);
    unsigned short* hS   = (unsigned short*)carve((size_t)NTOK * HSDIM * 2);
    int*   idxK   = (int*)carve((size_t)NTOK * 2 * 4);
    float* probK  = (float*)carve((size_t)NTOK * 2 * 4);
    int*   rowT   = (int*)carve((size_t)2 * NTOK * 4);
    float* rowW   = (float*)carve((size_t)2 * NTOK * 4);
    int*   tokSlot= (int*)carve((size_t)2 * NTOK * 4);
    int*   meta   = (int*)carve(256);

    // expert partials (bf16, 2N x C = 33.5 MB) alias the w1t+w2t region,
    // which is dead after gemm12 completes (stream-ordered before gemm3).
    unsigned short* pE = w1t;

    hipMemsetAsync(meta, 0, 256, stream);
    prep_kernel<<<P_TOTAL, 256, 0, stream>>>(
        x, Wg, W1, W2, W3, Ws1, Ws2, Ws3,
        xb, w1t, w2t, w3t, ws1t, ws2t, ws3t, idxK, probK, meta);
    offsets_kernel<<<1, 1, 0, stream>>>(meta);
    fill_kernel<<<NTOK / 256, 256, 0, stream>>>(idxK, probK, meta, rowT, rowW, tokSlot);

    gemm12_kernel<<<880 + 704, 512, 0, stream>>>(
        xb, w1t, w2t, ws1t, ws2t, hE, hS, rowT, meta);
    gemm3_kernel<<<512 + 1280, 256, 0, stream>>>(
        hE, hS, w3t, ws3t, out, pE, rowT, rowW, meta);
    combine_kernel<<<NTOK, 256, 0, stream>>>(out, pE, tokSlot, rowW);
}